// Round 4
// baseline (677.460 us; speedup 1.0000x reference)
//
#include <hip/hip_runtime.h>

// Quantized vector-matrix multiply: out[n] = sum_k (x[k]-Xzp)*Xs * (y[k,n]-Yzp)*Ys
// Exact-integer reformulation:
//   out[n] = Xs*Ys * ( sum_k xs[k]*y[k,n] - Yzp*sum_k xs[k] ),  xs = x - X_ZP
// Max |acc| ~ 8192*152*127 ~ 1.6e8 -> fits int32 exactly (more accurate than fp32 ref).
//
// Split-K GEMV: each block computes a [KCHUNK x 1024-col] int32 partial (chunk's
// zero-point correction folded in) and stores it to d_ws; a tiny second kernel sums
// SPLIT_K partials per column and applies the fp scale.
//
// R3->R4: SPLIT_K 64->128, unroll 16->8, __launch_bounds__(256,8) to force
// VGPR<=64 -> 32 waves/CU resident (occupancy/latency experiment; R3 ran ~3 TB/s
// effective, ~2x over the 85 us read floor).

constexpr int K = 8192;
constexpr int N = 16384;
constexpr float X_SCALE = 0.0215f;
constexpr int   X_ZP    = -25;
constexpr float Y_SCALE = 0.0176f;
constexpr int   Y_ZP    = 18;

constexpr int BLOCK = 256;
constexpr int VEC   = 4;                       // 16 B/lane loads
constexpr int COLS_PER_BLOCK = BLOCK * VEC;    // 1024
constexpr int NBLK_N = N / COLS_PER_BLOCK;     // 16
constexpr int SPLIT_K = 128;                   // 2048 blocks -> 8 blocks/CU, 32 waves/CU
constexpr int KCHUNK = K / SPLIT_K;            // 64
constexpr int N4 = N / 4;                      // vec4 elements per row

typedef int ivec4 __attribute__((ext_vector_type(4)));

__global__ __launch_bounds__(BLOCK, 8) void qgemv_partial(const int* __restrict__ x,
                                                          const ivec4* __restrict__ y,
                                                          ivec4* __restrict__ ws) {
    __shared__ int xs[KCHUNK];

    const int nb = blockIdx.x % NBLK_N;
    const int kc = blockIdx.x / NBLK_N;
    const int k0 = kc * KCHUNK;

    // Stage x chunk into LDS, pre-shifted by zero point (broadcast reads: conflict-free).
    if (threadIdx.x < KCHUNK)
        xs[threadIdx.x] = x[k0 + threadIdx.x] - X_ZP;
    __syncthreads();

    const int col4 = nb * (COLS_PER_BLOCK / 4) + threadIdx.x;  // vec4 column index
    const ivec4* yv = y + (size_t)k0 * N4 + col4;

    int acc0 = 0, acc1 = 0, acc2 = 0, acc3 = 0;
    int sx = 0;

    // 8 outstanding dwordx4 loads per lane (8 KiB in flight per wave, 256 KiB/CU at 32 waves).
#pragma unroll 8
    for (int k = 0; k < KCHUNK; ++k) {
        ivec4 v = __builtin_nontemporal_load(&yv[(size_t)k * N4]);
        int a = xs[k];
        sx   += a;
        acc0 += a * v.x;
        acc1 += a * v.y;
        acc2 += a * v.z;
        acc3 += a * v.w;
    }

    // Fold this chunk's zero-point correction into the partial -> reduce is a pure sum.
    const int corr = Y_ZP * sx;
    ivec4 p;
    p.x = acc0 - corr;
    p.y = acc1 - corr;
    p.z = acc2 - corr;
    p.w = acc3 - corr;
    ws[(size_t)kc * N4 + col4] = p;
}

__global__ __launch_bounds__(BLOCK) void qgemv_reduce(const ivec4* __restrict__ ws,
                                                      float* __restrict__ out) {
    const int t = blockIdx.x * BLOCK + threadIdx.x;  // 0 .. N4-1
    int sx = 0, sy = 0, sz = 0, sw = 0;
#pragma unroll 8
    for (int kc = 0; kc < SPLIT_K; ++kc) {
        ivec4 v = ws[(size_t)kc * N4 + t];
        sx += v.x; sy += v.y; sz += v.z; sw += v.w;
    }
    const float s = X_SCALE * Y_SCALE;
    float4 o;
    o.x = s * (float)sx;
    o.y = s * (float)sy;
    o.z = s * (float)sz;
    o.w = s * (float)sw;
    ((float4*)out)[t] = o;
}

extern "C" void kernel_launch(void* const* d_in, const int* in_sizes, int n_in,
                              void* d_out, int out_size, void* d_ws, size_t ws_size,
                              hipStream_t stream) {
    const int* x = (const int*)d_in[0];
    const ivec4* y = (const ivec4*)d_in[1];
    float* out = (float*)d_out;
    ivec4* ws = (ivec4*)d_ws;   // 128 x 4096 x 16 B = 8 MiB of the workspace

    qgemv_partial<<<NBLK_N * SPLIT_K, BLOCK, 0, stream>>>(x, y, ws);
    qgemv_reduce<<<N4 / BLOCK, BLOCK, 0, stream>>>(ws, out);
}

// Round 5
// 654.633 us; speedup vs baseline: 1.0349x; 1.0349x over previous
//
#include <hip/hip_runtime.h>

// Quantized vector-matrix multiply: out[n] = sum_k (x[k]-Xzp)*Xs * (y[k,n]-Yzp)*Ys
// Exact-integer reformulation:
//   out[n] = Xs*Ys * ( sum_k xs[k]*y[k,n] - Yzp*sum_k xs[k] ),  xs = x - X_ZP
// Max |acc| ~ 8192*152*127 ~ 1.6e8 -> fits int32 exactly.
//
// Split-K GEMV with int32 partials in d_ws + tiny reduce kernel (R3 structure).
//
// R4->R5: PHASE-STAGGERED k iteration. All prior variants advanced every block
// through row k in lockstep; with ~4 KiB HBM interleave a 64 KiB row maps to only
// 16 interleave units, so the whole GPU hammers a rotating ~16-channel subset
// (observed ~3.2 TB/s, insensitive to occupancy/epilogue). Each block now starts
// its chunk at row r0 = (13*kc + 7*nb) % KCHUNK and wraps — exact (sum is
// order-independent), spreads the instantaneous address footprint across all
// channels.

constexpr int K = 8192;
constexpr int N = 16384;
constexpr float X_SCALE = 0.0215f;
constexpr int   X_ZP    = -25;
constexpr float Y_SCALE = 0.0176f;
constexpr int   Y_ZP    = 18;

constexpr int BLOCK = 256;
constexpr int VEC   = 4;                       // 16 B/lane loads
constexpr int COLS_PER_BLOCK = BLOCK * VEC;    // 1024
constexpr int NBLK_N = N / COLS_PER_BLOCK;     // 16
constexpr int SPLIT_K = 128;                   // 2048 blocks -> 8 blocks/CU, 32 waves/CU
constexpr int KCHUNK = K / SPLIT_K;            // 64
constexpr int N4 = N / 4;                      // vec4 elements per row

typedef int ivec4 __attribute__((ext_vector_type(4)));

__global__ __launch_bounds__(BLOCK, 8) void qgemv_partial(const int* __restrict__ x,
                                                          const ivec4* __restrict__ y,
                                                          ivec4* __restrict__ ws) {
    __shared__ int xs[KCHUNK];

    const int nb = blockIdx.x % NBLK_N;
    const int kc = blockIdx.x / NBLK_N;
    const int k0 = kc * KCHUNK;

    // Stage x chunk into LDS, pre-shifted by zero point (broadcast reads: conflict-free).
    if (threadIdx.x < KCHUNK)
        xs[threadIdx.x] = x[k0 + threadIdx.x] - X_ZP;
    __syncthreads();

    const int col4 = nb * (COLS_PER_BLOCK / 4) + threadIdx.x;  // vec4 column index
    const ivec4* yv = y + (size_t)k0 * N4 + col4;

    // Per-block rotation phase: spread mod 8 AND mod 64 so concurrent blocks hit
    // disjoint interleave units.
    const int r0 = (13 * kc + 7 * nb) & (KCHUNK - 1);

    int acc0 = 0, acc1 = 0, acc2 = 0, acc3 = 0;
    int sx = 0;

#pragma unroll 8
    for (int i = 0; i < KCHUNK; ++i) {
        int k = r0 + i;
        if (k >= KCHUNK) k -= KCHUNK;
        ivec4 v = __builtin_nontemporal_load(&yv[(size_t)k * N4]);
        int a = xs[k];
        sx   += a;
        acc0 += a * v.x;
        acc1 += a * v.y;
        acc2 += a * v.z;
        acc3 += a * v.w;
    }

    // Fold this chunk's zero-point correction into the partial -> reduce is a pure sum.
    const int corr = Y_ZP * sx;
    ivec4 p;
    p.x = acc0 - corr;
    p.y = acc1 - corr;
    p.z = acc2 - corr;
    p.w = acc3 - corr;
    ws[(size_t)kc * N4 + col4] = p;
}

__global__ __launch_bounds__(BLOCK) void qgemv_reduce(const ivec4* __restrict__ ws,
                                                      float* __restrict__ out) {
    const int t = blockIdx.x * BLOCK + threadIdx.x;  // 0 .. N4-1
    int sx = 0, sy = 0, sz = 0, sw = 0;
#pragma unroll 8
    for (int kc = 0; kc < SPLIT_K; ++kc) {
        ivec4 v = ws[(size_t)kc * N4 + t];
        sx += v.x; sy += v.y; sz += v.z; sw += v.w;
    }
    const float s = X_SCALE * Y_SCALE;
    float4 o;
    o.x = s * (float)sx;
    o.y = s * (float)sy;
    o.z = s * (float)sz;
    o.w = s * (float)sw;
    ((float4*)out)[t] = o;
}

extern "C" void kernel_launch(void* const* d_in, const int* in_sizes, int n_in,
                              void* d_out, int out_size, void* d_ws, size_t ws_size,
                              hipStream_t stream) {
    const int* x = (const int*)d_in[0];
    const ivec4* y = (const ivec4*)d_in[1];
    float* out = (float*)d_out;
    ivec4* ws = (ivec4*)d_ws;   // 128 x 4096 x 16 B = 8 MiB of the workspace

    qgemv_partial<<<NBLK_N * SPLIT_K, BLOCK, 0, stream>>>(x, y, ws);
    qgemv_reduce<<<N4 / BLOCK, BLOCK, 0, stream>>>(ws, out);
}